// Round 14
// baseline (169.530 us; speedup 1.0000x reference)
//
#include <hip/hip_runtime.h>
#include <math.h>

#define BATCH 4
#define NPTS 8192
#define GS 24                  // 24^3 cells of 0.5 over [-6,6]^3
#define NCP 16384              // padded candidate cells per batch
#define QNCP 32768             // Morton query bins per batch (15-bit codes)
#define GMIN (-6.0f)
#define CS 0.5f
#define INVCS 2.0f
#define FINF 3.4e38f
#define QPT 64                 // queries per tile (one per lane)
#define NW 16                  // waves per knn_tile block

__device__ __forceinline__ int cellc(float v) {
    int c = (int)((v - GMIN) * INVCS);
    return min(max(c, 0), GS - 1);
}
__device__ __forceinline__ int mort5(int x) {   // spread 5 bits to every 3rd pos
    return (x & 1) | ((x & 2) << 2) | ((x & 4) << 4) | ((x & 8) << 6) | ((x & 16) << 8);
}

// branchless sorted top-3 update (R5-proven). Strict '<': incumbent wins ties.
#define INS3(d, idx, E0, E1, E2, I0, I1, I2) do {                     \
    bool c0 = (d) < E0, c1 = (d) < E1, c2 = (d) < E2;                 \
    float n1_ = __builtin_amdgcn_fmed3f(E0, E1, (d));                 \
    float n2_ = __builtin_amdgcn_fmed3f(E1, E2, (d));                 \
    I2 = c1 ? I1 : (c2 ? (idx) : I2);                                 \
    I1 = c0 ? I0 : (c1 ? (idx) : I1);                                 \
    I0 = c0 ? (idx) : I0;                                             \
    E0 = fminf(E0, (d)); E1 = n1_; E2 = n2_;                          \
} while (0)

// shared IDW epilogue: id* are global sorted candidate indices
__device__ __forceinline__ void idw_write(
    float qx, float qy, float qz, int n0, int n1, int n2,
    const float4* __restrict__ ckey, const float4* __restrict__ cflow,
    float* __restrict__ out, int b, int origj)
{
    float wsum = 0.f, f2x = 0.f, f2y = 0.f, f2z = 0.f;
    int idxs[3] = { n0, n1, n2 };
    #pragma unroll
    for (int k = 0; k < 3; ++k) {
        int id = idxs[k];
        float4 c = ckey[id];
        float cx = -0.5f * c.x, cy = -0.5f * c.y, cz = -0.5f * c.z;  // exact
        float dx = cx - qx, dy = cy - qy, dz = cz - qz;
        float dist = sqrtf(fmaf(dx, dx, fmaf(dy, dy, dz * dz)));
        dist = fmaxf(dist, 1e-10f);
        float w = 1.0f / dist;
        wsum += w;
        float4 fl = cflow[id];
        f2x = fmaf(w, fl.x, f2x);
        f2y = fmaf(w, fl.y, f2y);
        f2z = fmaf(w, fl.z, f2z);
    }
    float r = 1.0f / wsum;
    float* ob = out + b * 3 * NPTS;
    ob[origj]            = qx - f2x * r;
    ob[NPTS + origj]     = qy - f2y * r;
    ob[2 * NPTS + origj] = qz - f2z * r;
}

// ---------------------------------------------------------------------------
// K1: histogram candidates (linear cells) and queries (Morton bins).
// ---------------------------------------------------------------------------
__global__ __launch_bounds__(256) void bin_both(
    const float* __restrict__ xyz1, const float* __restrict__ xyz2,
    const float* __restrict__ flow1, int* __restrict__ counts_c,
    int* __restrict__ counts_q)
{
    int t = blockIdx.x * 256 + threadIdx.x;       // 2*BATCH*NPTS threads
    if (t < BATCH * NPTS) {
        int b = t >> 13, n = t & (NPTS - 1);
        const float* x = xyz1 + b * 3 * NPTS + n;
        const float* f = flow1 + b * 3 * NPTS + n;
        float wx = x[0] + f[0], wy = x[NPTS] + f[NPTS], wz = x[2*NPTS] + f[2*NPTS];
        int loc = (cellc(wz) * GS + cellc(wy)) * GS + cellc(wx);
        atomicAdd(&counts_c[b * NCP + loc], 1);
    } else {
        int tq = t - BATCH * NPTS;
        int b = tq >> 13, n = tq & (NPTS - 1);
        const float* q = xyz2 + b * 3 * NPTS + n;
        int mc = mort5(cellc(q[0])) | (mort5(cellc(q[NPTS])) << 1)
               | (mort5(cellc(q[2*NPTS])) << 2);
        atomicAdd(&counts_q[b * QNCP + mc], 1);
    }
}

// ---------------------------------------------------------------------------
// K2: exclusive prefix scan via shfl. Blocks 0-3: candidate cells (16384 =
// 4 chunks of 4096); blocks 4-7: query Morton bins (32768 = 8 chunks).
// ---------------------------------------------------------------------------
__global__ __launch_bounds__(1024) void scan_chunks(
    const int* __restrict__ cc, int* __restrict__ cs, int* __restrict__ ccur,
    const int* __restrict__ qc, int* __restrict__ qs, int* __restrict__ qcur)
{
    __shared__ int wsum[16];
    __shared__ int wpre[16];
    __shared__ int ctot;
    int blk = blockIdx.x, t = (int)threadIdx.x;
    int lane = t & 63, wid = t >> 6;
    const int* cnts; int* oS; int* oC; int batch, ncells;
    if (blk < 4) { batch = blk;     cnts = cc; oS = cs; oC = ccur; ncells = NCP;  }
    else         { batch = blk - 4; cnts = qc; oS = qs; oC = qcur; ncells = QNCP; }
    int base = batch * ncells;
    int carry = batch * NPTS;
    for (int ch = 0; ch < ncells; ch += 4096) {
        int4 v = *(const int4*)&cnts[base + ch + t * 4];
        int tsum = v.x + v.y + v.z + v.w;
        int incl = tsum;
        #pragma unroll
        for (int o = 1; o < 64; o <<= 1) {
            int n = __shfl_up(incl, o);
            if (lane >= o) incl += n;
        }
        if (lane == 63) wsum[wid] = incl;
        __syncthreads();
        if (t < 16) {
            int wv = wsum[t];
            int wincl = wv;
            #pragma unroll
            for (int o = 1; o < 16; o <<= 1) {
                int n = __shfl_up(wincl, o);
                if (t >= o) wincl += n;
            }
            wpre[t] = wincl - wv;
            if (t == 15) ctot = wincl;
        }
        __syncthreads();
        int excl = carry + wpre[wid] + (incl - tsum);
        int4 o4; o4.x = excl; o4.y = excl + v.x; o4.z = o4.y + v.y; o4.w = o4.z + v.z;
        *(int4*)&oS[base + ch + t * 4] = o4;
        *(int4*)&oC[base + ch + t * 4] = o4;
        carry += ctot;
        __syncthreads();
    }
    if (t == 0) oS[base + ncells] = carry;   // sentinel
}

// ---------------------------------------------------------------------------
// K3: scatter candidates (key+flow, cell order) AND queries (coords+orig idx,
// Morton order). One kernel, two halves of the grid.
// ---------------------------------------------------------------------------
__global__ __launch_bounds__(256) void scatter_both(
    const float* __restrict__ xyz1, const float* __restrict__ xyz2,
    const float* __restrict__ flow1, int* __restrict__ ccur,
    int* __restrict__ qcur, float4* __restrict__ ckey,
    float4* __restrict__ cflow, float4* __restrict__ qpos)
{
    int t = blockIdx.x * 256 + threadIdx.x;       // 2*BATCH*NPTS threads
    if (t < BATCH * NPTS) {
        int b = t >> 13, n = t & (NPTS - 1);
        const float* x = xyz1 + b * 3 * NPTS + n;
        const float* f = flow1 + b * 3 * NPTS + n;
        float fx = f[0], fy = f[NPTS], fz = f[2*NPTS];
        float wx = x[0] + fx, wy = x[NPTS] + fy, wz = x[2*NPTS] + fz;
        float nrm = fmaf(wx, wx, fmaf(wy, wy, wz * wz));
        int loc = (cellc(wz) * GS + cellc(wy)) * GS + cellc(wx);
        int pos = atomicAdd(&ccur[b * NCP + loc], 1);
        ckey[pos]  = make_float4(-2.0f*wx, -2.0f*wy, -2.0f*wz, nrm);
        cflow[pos] = make_float4(fx, fy, fz, 0.0f);
    } else {
        int tq = t - BATCH * NPTS;
        int b = tq >> 13, n = tq & (NPTS - 1);
        const float* q = xyz2 + b * 3 * NPTS + n;
        float qx = q[0], qy = q[NPTS], qz = q[2*NPTS];
        int mc = mort5(cellc(qx)) | (mort5(cellc(qy)) << 1) | (mort5(cellc(qz)) << 2);
        int pos = atomicAdd(&qcur[b * QNCP + mc], 1);
        qpos[pos] = make_float4(qx, qy, qz, __int_as_float(n));
    }
}

// ---------------------------------------------------------------------------
// K4: main pass — s_load streaming over per-ROW windows, 16-wave chunked
// round-robin. Block = 1024 thr = 16 waves; lane l = query l of the tile's
// 64 Morton-sorted queries (every wave holds all 64, recomputes identical
// windows -> cnt stays uniform). Per (z,y) row: x-window reduced over lanes
// ACTIVE for that row (|hz-z|<=1 && |hy-y|<=1) -> tight windows (no raster
// wrap blowup). Rows split into <=64-pt chunks dealt (cnt&15)==w -> heavy
// central tiles balance across all 16 waves. Row runs readfirstlane'd so
// the point loop is wave-uniform -> ckey[k] scalarizes (R7/R13-proven).
// Final LDS merge of 16 partials; per-query +-1-box margin test -> exact;
// unresolved -> compacted fallback list.
// ---------------------------------------------------------------------------
__global__ __launch_bounds__(1024) void knn_tile(
    const float4* __restrict__ qpos, const float4* __restrict__ ckey,
    const float4* __restrict__ cflow, const int* __restrict__ cstart,
    int* __restrict__ fbcnt, int* __restrict__ fblist, float* __restrict__ out)
{
    __shared__ float md[NW][QPT][3];
    __shared__ int   mi[NW][QPT][3];

    int tile = blockIdx.x;               // BATCH*128
    int b = tile >> 7, ti = tile & 127;
    int t = (int)threadIdx.x;
    int w = t >> 6, l = t & 63;
    int qbase = b * NPTS + ti * QPT;

    float4 qp = qpos[qbase + l];
    float qx = qp.x, qy = qp.y, qz = qp.z;
    int origj = __float_as_int(qp.w);
    float qn = fmaf(qx, qx, fmaf(qy, qy, qz * qz));
    int hx = cellc(qx), hy = cellc(qy), hz = cellc(qz);

    int zmn = hz, zmx = hz;
    #pragma unroll
    for (int o = 32; o >= 1; o >>= 1) {
        zmn = min(zmn, __shfl_xor(zmn, o));
        zmx = max(zmx, __shfl_xor(zmx, o));
    }
    int loz = max(zmn - 1, 0), hiz = min(zmx + 1, GS - 1);

    float e0 = FINF, e1 = FINF, e2 = FINF;
    int   i0 = 0, i1 = 0, i2 = 0;
    int cnt = 0;
    int bN = b * NCP;

    for (int z = loz; z <= hiz; ++z) {
        bool actz = (hz - z <= 1) && (z - hz <= 1);
        int ymn = actz ? hy : 1000, ymx = actz ? hy : -1000;
        #pragma unroll
        for (int o = 32; o >= 1; o >>= 1) {
            ymn = min(ymn, __shfl_xor(ymn, o));
            ymx = max(ymx, __shfl_xor(ymx, o));
        }
        if (ymn == 1000) continue;                 // no query needs this slab
        int ylo = max(ymn - 1, 0), yhi = min(ymx + 1, GS - 1);

        for (int y = ylo; y <= yhi; ++y) {
            bool acty = actz && (hy - y <= 1) && (y - hy <= 1);
            int xmn = acty ? hx : 1000, xmx = acty ? hx : -1000;
            #pragma unroll
            for (int o = 32; o >= 1; o >>= 1) {
                xmn = min(xmn, __shfl_xor(xmn, o));
                xmx = max(xmx, __shfl_xor(xmx, o));
            }
            if (xmn == 1000) continue;             // no query needs this row
            int xlo = max(xmn - 1, 0), xhi = min(xmx + 1, GS - 1);

            int rb = bN + (z * GS + y) * GS;
            int st = __builtin_amdgcn_readfirstlane(cstart[rb + xlo]);
            int en = __builtin_amdgcn_readfirstlane(cstart[rb + xhi + 1]);
            for (int c0 = st; c0 < en; c0 += 64) { // <=64-pt chunks round-robin
                if ((cnt++ & (NW - 1)) != w) continue;
                int ce = min(c0 + 64, en);
                for (int k = c0; k < ce; ++k) {    // k wave-uniform -> s_load
                    float4 c = ckey[k];
                    float d = fmaf(c.x, qx, fmaf(c.y, qy, fmaf(c.z, qz, c.w)));
                    INS3(d, k, e0, e1, e2, i0, i1, i2);
                }
            }
        }
    }

    md[w][l][0] = e0; md[w][l][1] = e1; md[w][l][2] = e2;
    mi[w][l][0] = i0; mi[w][l][1] = i1; mi[w][l][2] = i2;
    __syncthreads();

    if (t < QPT) {
        float m0 = FINF, m1 = FINF, m2 = FINF;
        int   n0 = 0, n1 = 0, n2 = 0;
        #pragma unroll
        for (int ww = 0; ww < NW; ++ww) {
            INS3(md[ww][t][0], mi[ww][t][0], m0, m1, m2, n0, n1, n2);
            INS3(md[ww][t][1], mi[ww][t][1], m0, m1, m2, n0, n1, n2);
            INS3(md[ww][t][2], mi[ww][t][2], m0, m1, m2, n0, n1, n2);
        }
        // per-query margin: distance to own +-1-cell-box faces (grid-edge skipped)
        float mg = FINF;
        if (hx > 1)      mg = fminf(mg, qx - (GMIN + (hx - 1) * CS));
        if (hx < GS - 2) mg = fminf(mg, (GMIN + (hx + 2) * CS) - qx);
        if (hy > 1)      mg = fminf(mg, qy - (GMIN + (hy - 1) * CS));
        if (hy < GS - 2) mg = fminf(mg, (GMIN + (hy + 2) * CS) - qy);
        if (hz > 1)      mg = fminf(mg, qz - (GMIN + (hz - 1) * CS));
        if (hz < GS - 2) mg = fminf(mg, (GMIN + (hz + 2) * CS) - qz);
        if (m2 + qn <= mg * mg) {
            idw_write(qx, qy, qz, n0, n1, n2, ckey, cflow, out, b, origj);
        } else {
            int p = atomicAdd(&fbcnt[b], 1);
            fblist[b * NPTS + p] = ti * QPT + t;   // batch-local sorted position
        }
    }
}

// ---------------------------------------------------------------------------
// K5: wave-per-query fallback (R12-proven). Lane ln scans candidates
// ln, ln+64, ... (coalesced vector loads), butterfly shfl merge, lane 0
// writes. Worst-case grid, wave-uniform early exit.
// ---------------------------------------------------------------------------
__global__ __launch_bounds__(256) void fb_wave(
    const float4* __restrict__ qpos, const float4* __restrict__ ckey,
    const float4* __restrict__ cflow, const int* __restrict__ fbcnt,
    const int* __restrict__ fblist, float* __restrict__ out)
{
    int blk = blockIdx.x;                 // BATCH * NPTS/4 = 8192
    int b = blk >> 11, grp = blk & 2047;
    int t = (int)threadIdx.x;
    int w = t >> 6, ln = t & 63;
    int cnt = fbcnt[b];
    int idx = grp * 4 + w;
    if (idx >= cnt) return;               // wave-uniform exit

    int js = fblist[b * NPTS + idx];
    float4 qp = qpos[b * NPTS + js];
    float qx = qp.x, qy = qp.y, qz = qp.z;
    int origj = __float_as_int(qp.w);

    const float4* src = ckey + b * NPTS;

    float e0 = FINF, e1 = FINF, e2 = FINF;
    int   i0 = 0, i1 = 0, i2 = 0;
    #pragma unroll 4
    for (int k = ln; k < NPTS; k += 64) {
        float4 c = src[k];
        float d = fmaf(c.x, qx, fmaf(c.y, qy, fmaf(c.z, qz, c.w)));
        INS3(d, k, e0, e1, e2, i0, i1, i2);
    }
    #pragma unroll
    for (int o = 1; o < 64; o <<= 1) {
        float r0 = __shfl_xor(e0, o), r1 = __shfl_xor(e1, o), r2 = __shfl_xor(e2, o);
        int   s0 = __shfl_xor(i0, o), s1 = __shfl_xor(i1, o), s2 = __shfl_xor(i2, o);
        INS3(r0, s0, e0, e1, e2, i0, i1, i2);
        INS3(r1, s1, e0, e1, e2, i0, i1, i2);
        INS3(r2, s2, e0, e1, e2, i0, i1, i2);
    }
    if (ln == 0) {
        idw_write(qx, qy, qz, b * NPTS + i0, b * NPTS + i1, b * NPTS + i2,
                  ckey, cflow, out, b, origj);
    }
}

// ---------------------------------------------------------------------------
// Launcher. Workspace ~4.2 MB.
// ---------------------------------------------------------------------------
extern "C" void kernel_launch(void* const* d_in, const int* in_sizes, int n_in,
                              void* d_out, int out_size, void* d_ws, size_t ws_size,
                              hipStream_t stream)
{
    const float* xyz1  = (const float*)d_in[0];
    const float* xyz2  = (const float*)d_in[1];
    const float* flow1 = (const float*)d_in[2];
    float* out = (float*)d_out;

    char* p = (char*)d_ws;
    float4* ckey     = (float4*)p;  p += (size_t)BATCH * NPTS * 16;
    float4* cflow    = (float4*)p;  p += (size_t)BATCH * NPTS * 16;
    float4* qpos     = (float4*)p;  p += (size_t)BATCH * NPTS * 16;
    int*    counts_c = (int*)p;     p += (size_t)BATCH * NCP * 4;
    int*    counts_q = (int*)p;     p += (size_t)BATCH * QNCP * 4;
    int*    fbcnt    = (int*)p;     p += 16;
    int*    cstart   = (int*)p;     p += ((size_t)BATCH * NCP + 4) * 4;
    int*    ccur     = (int*)p;     p += (size_t)BATCH * NCP * 4;
    int*    qstart   = (int*)p;     p += ((size_t)BATCH * QNCP + 4) * 4;
    int*    qcur     = (int*)p;     p += (size_t)BATCH * QNCP * 4;
    int*    fblist   = (int*)p;

    // zero counts_c + counts_q + fbcnt in one shot (contiguous)
    hipMemsetAsync(counts_c, 0, (size_t)BATCH * (NCP + QNCP) * 4 + 16, stream);
    bin_both    <<<2 * BATCH * NPTS / 256, 256, 0, stream>>>(xyz1, xyz2, flow1, counts_c, counts_q);
    scan_chunks <<<8, 1024, 0, stream>>>(counts_c, cstart, ccur, counts_q, qstart, qcur);
    scatter_both<<<2 * BATCH * NPTS / 256, 256, 0, stream>>>(xyz1, xyz2, flow1, ccur, qcur, ckey, cflow, qpos);
    knn_tile    <<<BATCH * (NPTS / QPT), 1024, 0, stream>>>(qpos, ckey, cflow, cstart, fbcnt, fblist, out);
    fb_wave     <<<BATCH * (NPTS / 4), 256, 0, stream>>>(qpos, ckey, cflow, fbcnt, fblist, out);
}

// Round 15
// 134.376 us; speedup vs baseline: 1.2616x; 1.2616x over previous
//
#include <hip/hip_runtime.h>
#include <math.h>

#define BATCH 4
#define NPTS 8192
#define GS 24                  // candidate grid 24^3, cell 0.5 over [-6,6]^3
#define NCP 16384              // padded candidate cells per batch
#define QB 4096                // query Morton bins (16^3, 12-bit codes)
#define GMIN (-6.0f)
#define CS 0.5f
#define INVCS 2.0f
#define FINF 3.4e38f
#define QPT 32                 // queries per tile
#define BUF 1536               // LDS staging slots (float4 + int idx)

__device__ __forceinline__ int cellc(float v) {
    int c = (int)((v - GMIN) * INVCS);
    return min(max(c, 0), GS - 1);
}
__device__ __forceinline__ int qc16(float v) {   // coarse 16-cell coord
    int c = (int)((v - GMIN) * (16.0f / 12.0f));
    return min(max(c, 0), 15);
}
__device__ __forceinline__ int mort4(int x) {    // spread 4 bits to every 3rd pos
    return (x & 1) | ((x & 2) << 2) | ((x & 4) << 4) | ((x & 8) << 6);
}

// branchless sorted top-3 update (R5-proven). Strict '<': incumbent wins ties.
#define INS3(d, idx, E0, E1, E2, I0, I1, I2) do {                     \
    bool c0 = (d) < E0, c1 = (d) < E1, c2 = (d) < E2;                 \
    float n1_ = __builtin_amdgcn_fmed3f(E0, E1, (d));                 \
    float n2_ = __builtin_amdgcn_fmed3f(E1, E2, (d));                 \
    I2 = c1 ? I1 : (c2 ? (idx) : I2);                                 \
    I1 = c0 ? I0 : (c1 ? (idx) : I1);                                 \
    I0 = c0 ? (idx) : I0;                                             \
    E0 = fminf(E0, (d)); E1 = n1_; E2 = n2_;                          \
} while (0)

// shared IDW epilogue: id* are global sorted candidate indices
__device__ __forceinline__ void idw_write(
    float qx, float qy, float qz, int n0, int n1, int n2,
    const float4* __restrict__ ckey, const float4* __restrict__ cflow,
    float* __restrict__ out, int b, int origj)
{
    float wsum = 0.f, f2x = 0.f, f2y = 0.f, f2z = 0.f;
    int idxs[3] = { n0, n1, n2 };
    #pragma unroll
    for (int k = 0; k < 3; ++k) {
        int id = idxs[k];
        float4 c = ckey[id];
        float cx = -0.5f * c.x, cy = -0.5f * c.y, cz = -0.5f * c.z;  // exact
        float dx = cx - qx, dy = cy - qy, dz = cz - qz;
        float dist = sqrtf(fmaf(dx, dx, fmaf(dy, dy, dz * dz)));
        dist = fmaxf(dist, 1e-10f);
        float w = 1.0f / dist;
        wsum += w;
        float4 fl = cflow[id];
        f2x = fmaf(w, fl.x, f2x);
        f2y = fmaf(w, fl.y, f2y);
        f2z = fmaf(w, fl.z, f2z);
    }
    float r = 1.0f / wsum;
    float* ob = out + b * 3 * NPTS;
    ob[origj]            = qx - f2x * r;
    ob[NPTS + origj]     = qy - f2y * r;
    ob[2 * NPTS + origj] = qz - f2z * r;
}

// ---------------------------------------------------------------------------
// K1: histogram candidates (fine cells) and queries (coarse Morton bins).
// ---------------------------------------------------------------------------
__global__ __launch_bounds__(256) void bin_both(
    const float* __restrict__ xyz1, const float* __restrict__ xyz2,
    const float* __restrict__ flow1, int* __restrict__ counts_c,
    int* __restrict__ counts_q)
{
    int t = blockIdx.x * 256 + threadIdx.x;       // 2*BATCH*NPTS threads
    if (t < BATCH * NPTS) {
        int b = t >> 13, n = t & (NPTS - 1);
        const float* x = xyz1 + b * 3 * NPTS + n;
        const float* f = flow1 + b * 3 * NPTS + n;
        float wx = x[0] + f[0], wy = x[NPTS] + f[NPTS], wz = x[2*NPTS] + f[2*NPTS];
        int loc = (cellc(wz) * GS + cellc(wy)) * GS + cellc(wx);
        atomicAdd(&counts_c[b * NCP + loc], 1);
    } else {
        int tq = t - BATCH * NPTS;
        int b = tq >> 13, n = tq & (NPTS - 1);
        const float* q = xyz2 + b * 3 * NPTS + n;
        int mc = mort4(qc16(q[0])) | (mort4(qc16(q[NPTS])) << 1)
               | (mort4(qc16(q[2*NPTS])) << 2);
        atomicAdd(&counts_q[b * QB + mc], 1);
    }
}

// ---------------------------------------------------------------------------
// K2: exclusive prefix scan via shfl. Blocks 0-3: candidate cells (16384 =
// 4 chunks of 4096); blocks 4-7: query bins (4096 = 1 chunk).
// ---------------------------------------------------------------------------
__global__ __launch_bounds__(1024) void scan_chunks(
    const int* __restrict__ cc, int* __restrict__ cs, int* __restrict__ ccur,
    const int* __restrict__ qc, int* __restrict__ qs, int* __restrict__ qcur)
{
    __shared__ int wsum[16];
    __shared__ int wpre[16];
    __shared__ int ctot;
    int blk = blockIdx.x, t = (int)threadIdx.x;
    int lane = t & 63, wid = t >> 6;
    const int* cnts; int* oS; int* oC; int batch, ncells;
    if (blk < 4) { batch = blk;     cnts = cc; oS = cs; oC = ccur; ncells = NCP; }
    else         { batch = blk - 4; cnts = qc; oS = qs; oC = qcur; ncells = QB;  }
    int base = batch * ncells;
    int carry = batch * NPTS;
    for (int ch = 0; ch < ncells; ch += 4096) {
        int4 v = *(const int4*)&cnts[base + ch + t * 4];
        int tsum = v.x + v.y + v.z + v.w;
        int incl = tsum;
        #pragma unroll
        for (int o = 1; o < 64; o <<= 1) {
            int n = __shfl_up(incl, o);
            if (lane >= o) incl += n;
        }
        if (lane == 63) wsum[wid] = incl;
        __syncthreads();
        if (t < 16) {
            int wv = wsum[t];
            int wincl = wv;
            #pragma unroll
            for (int o = 1; o < 16; o <<= 1) {
                int n = __shfl_up(wincl, o);
                if (t >= o) wincl += n;
            }
            wpre[t] = wincl - wv;
            if (t == 15) ctot = wincl;
        }
        __syncthreads();
        int excl = carry + wpre[wid] + (incl - tsum);
        int4 o4; o4.x = excl; o4.y = excl + v.x; o4.z = o4.y + v.y; o4.w = o4.z + v.z;
        *(int4*)&oS[base + ch + t * 4] = o4;
        *(int4*)&oC[base + ch + t * 4] = o4;
        carry += ctot;
        __syncthreads();
    }
    if (t == 0) oS[base + ncells] = carry;   // sentinel
}

// ---------------------------------------------------------------------------
// K3: scatter candidates (key+flow, cell order) AND queries (coords+orig idx,
// Morton order). One kernel, two halves of the grid.
// ---------------------------------------------------------------------------
__global__ __launch_bounds__(256) void scatter_both(
    const float* __restrict__ xyz1, const float* __restrict__ xyz2,
    const float* __restrict__ flow1, int* __restrict__ ccur,
    int* __restrict__ qcur, float4* __restrict__ ckey,
    float4* __restrict__ cflow, float4* __restrict__ qpos)
{
    int t = blockIdx.x * 256 + threadIdx.x;       // 2*BATCH*NPTS threads
    if (t < BATCH * NPTS) {
        int b = t >> 13, n = t & (NPTS - 1);
        const float* x = xyz1 + b * 3 * NPTS + n;
        const float* f = flow1 + b * 3 * NPTS + n;
        float fx = f[0], fy = f[NPTS], fz = f[2*NPTS];
        float wx = x[0] + fx, wy = x[NPTS] + fy, wz = x[2*NPTS] + fz;
        float nrm = fmaf(wx, wx, fmaf(wy, wy, wz * wz));
        int loc = (cellc(wz) * GS + cellc(wy)) * GS + cellc(wx);
        int pos = atomicAdd(&ccur[b * NCP + loc], 1);
        ckey[pos]  = make_float4(-2.0f*wx, -2.0f*wy, -2.0f*wz, nrm);
        cflow[pos] = make_float4(fx, fy, fz, 0.0f);
    } else {
        int tq = t - BATCH * NPTS;
        int b = tq >> 13, n = tq & (NPTS - 1);
        const float* q = xyz2 + b * 3 * NPTS + n;
        float qx = q[0], qy = q[NPTS], qz = q[2*NPTS];
        int mc = mort4(qc16(qx)) | (mort4(qc16(qy)) << 1) | (mort4(qc16(qz)) << 2);
        int pos = atomicAdd(&qcur[b * QB + mc], 1);
        qpos[pos] = make_float4(qx, qy, qz, __int_as_float(n));
    }
}

// ---------------------------------------------------------------------------
// K4: main pass — R12's accumulate-then-stream, upgraded with Morton tiles
// and per-row x-windows.
// Block = 256 thr = 32 Morton-sorted queries (l = t&31) x 8 slot-streams
// (so = t>>5). Per z-slab (|hz-z|<=1 active): y-window over active lanes;
// per row y: x-window over row-active lanes, row run [st,len) stored in
// lane r's registers. shfl_up scan over row lengths -> offsets; rows copied
// cooperatively (wave w takes rows w, w+4, ...) into a 1536-slot LDS buffer
// accumulating ACROSS slabs; streamed in long broadcast passes when full.
// Resolve via per-query +-1-cell-box margin (grid-edge faces skipped) ->
// exact. Unresolved -> compacted per-batch fallback list.
// ---------------------------------------------------------------------------
#define STREAM(lim) do {                                              \
    for (int i_ = so; i_ < (lim); i_ += 8) {                          \
        float4 c_ = sc[i_];                                           \
        int kk_ = sidx[i_];                                           \
        float d_ = fmaf(c_.x, qx, fmaf(c_.y, qy, fmaf(c_.z, qz, c_.w))); \
        INS3(d_, kk_, e0, e1, e2, i0, i1, i2);                        \
    }                                                                 \
} while (0)

__global__ __launch_bounds__(256) void knn_tile(
    const float4* __restrict__ qpos, const float4* __restrict__ ckey,
    const float4* __restrict__ cflow, const int* __restrict__ cstart,
    int* __restrict__ fbcnt, int* __restrict__ fblist, float* __restrict__ out)
{
    __shared__ float4 sc[BUF];
    __shared__ int    sidx[BUF];
    float* md = (float*)&sc[0];                       // [8][32][3], aliases sc
    int*   mi = (int*)((char*)&sc[0] + 3072);

    int tile = blockIdx.x;               // BATCH*256
    int b = tile >> 8, ti = tile & 255;
    int t = (int)threadIdx.x;
    int lane = t & 63, so = t >> 5, l = t & 31, w = t >> 6;
    int qbase = b * NPTS + ti * QPT;

    float4 qp = qpos[qbase + l];
    float qx = qp.x, qy = qp.y, qz = qp.z;
    int origj = __float_as_int(qp.w);
    float qn = fmaf(qx, qx, fmaf(qy, qy, qz * qz));
    int hx = cellc(qx), hy = cellc(qy), hz = cellc(qz);

    int zmn = hz, zmx = hz;
    #pragma unroll
    for (int o = 32; o >= 1; o >>= 1) {
        zmn = min(zmn, __shfl_xor(zmn, o));
        zmx = max(zmx, __shfl_xor(zmx, o));
    }
    int loz = max(zmn - 1, 0), hiz = min(zmx + 1, GS - 1);

    float e0 = FINF, e1 = FINF, e2 = FINF;
    int   i0 = 0, i1 = 0, i2 = 0;
    int bufofs = 0;
    int bN = b * NCP;

    for (int z = loz; z <= hiz; ++z) {
        bool actz = (hz - z <= 1) && (z - hz <= 1);
        int ymn = actz ? hy : 1000, ymx = actz ? hy : -1000;
        #pragma unroll
        for (int o = 32; o >= 1; o >>= 1) {
            ymn = min(ymn, __shfl_xor(ymn, o));
            ymx = max(ymx, __shfl_xor(ymx, o));
        }
        if (ymn == 1000) continue;                 // no query needs this slab
        int ylo = max(ymn - 1, 0), yhi = min(ymx + 1, GS - 1);
        int nrows = yhi - ylo + 1;                 // Morton tiles: ~4-6

        // per-row x-windows; lane r holds row r's [strt, rlen)
        int strt = 0, rlen = 0;
        for (int r = 0; r < nrows; ++r) {
            int y = ylo + r;
            bool acty = actz && (hy - y <= 1) && (y - hy <= 1);
            int xmn = acty ? hx : 1000, xmx = acty ? hx : -1000;
            #pragma unroll
            for (int o = 32; o >= 1; o >>= 1) {
                xmn = min(xmn, __shfl_xor(xmn, o));
                xmx = max(xmx, __shfl_xor(xmx, o));
            }
            if (xmn != 1000 && lane == r) {
                int xlo = max(xmn - 1, 0), xhi = min(xmx + 1, GS - 1);
                int rb = bN + (z * GS + y) * GS;
                strt = cstart[rb + xlo];
                rlen = cstart[rb + xhi + 1] - strt;
            }
        }

        int incl = rlen;
        #pragma unroll
        for (int o = 1; o < 64; o <<= 1) {
            int n = __shfl_up(incl, o);
            if (lane >= o) incl += n;
        }
        int excl = incl - rlen;
        int T = __shfl(incl, 63);

        int copied = 0;
        while (copied < T) {                       // uniform loop
            int cnt = min(T - copied, BUF - bufofs);
            for (int r = w; r < nrows; r += 4) {   // wave w copies rows w,w+4,..
                int rofs = __shfl(excl, r);
                int rst  = __shfl(strt, r);
                int rln  = __shfl(rlen, r);
                int lo = max(rofs, copied), hi = min(rofs + rln, copied + cnt);
                for (int i = lo + lane; i < hi; i += 64) {
                    int dst = bufofs + (i - copied);
                    int src = rst + (i - rofs);
                    sc[dst] = ckey[src];
                    sidx[dst] = src;
                }
            }
            bufofs += cnt; copied += cnt;
            if (bufofs == BUF) {                   // uniform
                __syncthreads();
                STREAM(BUF);
                __syncthreads();
                bufofs = 0;
            }
        }
    }
    __syncthreads();
    if (bufofs > 0) STREAM(bufofs);                // uniform
    __syncthreads();                               // sc reused as md/mi below

    md[(so * 32 + l) * 3 + 0] = e0;  mi[(so * 32 + l) * 3 + 0] = i0;
    md[(so * 32 + l) * 3 + 1] = e1;  mi[(so * 32 + l) * 3 + 1] = i1;
    md[(so * 32 + l) * 3 + 2] = e2;  mi[(so * 32 + l) * 3 + 2] = i2;
    __syncthreads();

    if (t < QPT) {
        float m0 = FINF, m1 = FINF, m2 = FINF;
        int   n0 = 0, n1 = 0, n2 = 0;
        #pragma unroll
        for (int ss = 0; ss < 8; ++ss) {
            int bx = (ss * 32 + t) * 3;
            INS3(md[bx],     mi[bx],     m0, m1, m2, n0, n1, n2);
            INS3(md[bx + 1], mi[bx + 1], m0, m1, m2, n0, n1, n2);
            INS3(md[bx + 2], mi[bx + 2], m0, m1, m2, n0, n1, n2);
        }
        // per-query margin: distance to own +-1-cell-box faces (grid-edge skipped)
        float mg = FINF;
        if (hx > 1)      mg = fminf(mg, qx - (GMIN + (hx - 1) * CS));
        if (hx < GS - 2) mg = fminf(mg, (GMIN + (hx + 2) * CS) - qx);
        if (hy > 1)      mg = fminf(mg, qy - (GMIN + (hy - 1) * CS));
        if (hy < GS - 2) mg = fminf(mg, (GMIN + (hy + 2) * CS) - qy);
        if (hz > 1)      mg = fminf(mg, qz - (GMIN + (hz - 1) * CS));
        if (hz < GS - 2) mg = fminf(mg, (GMIN + (hz + 2) * CS) - qz);
        if (m2 + qn <= mg * mg) {
            idw_write(qx, qy, qz, n0, n1, n2, ckey, cflow, out, b, origj);
        } else {
            int p = atomicAdd(&fbcnt[b], 1);
            fblist[b * NPTS + p] = ti * QPT + t;   // batch-local sorted position
        }
    }
}

// ---------------------------------------------------------------------------
// K5: wave-per-query fallback (R12-proven). Lane ln scans candidates
// ln, ln+64, ... (coalesced vector loads), butterfly shfl merge, lane 0
// writes. Worst-case grid, wave-uniform early exit.
// ---------------------------------------------------------------------------
__global__ __launch_bounds__(256) void fb_wave(
    const float4* __restrict__ qpos, const float4* __restrict__ ckey,
    const float4* __restrict__ cflow, const int* __restrict__ fbcnt,
    const int* __restrict__ fblist, float* __restrict__ out)
{
    int blk = blockIdx.x;                 // BATCH * NPTS/4 = 8192
    int b = blk >> 11, grp = blk & 2047;
    int t = (int)threadIdx.x;
    int w = t >> 6, ln = t & 63;
    int cnt = fbcnt[b];
    int idx = grp * 4 + w;
    if (idx >= cnt) return;               // wave-uniform exit

    int js = fblist[b * NPTS + idx];
    float4 qp = qpos[b * NPTS + js];
    float qx = qp.x, qy = qp.y, qz = qp.z;
    int origj = __float_as_int(qp.w);

    const float4* src = ckey + b * NPTS;

    float e0 = FINF, e1 = FINF, e2 = FINF;
    int   i0 = 0, i1 = 0, i2 = 0;
    #pragma unroll 4
    for (int k = ln; k < NPTS; k += 64) {
        float4 c = src[k];
        float d = fmaf(c.x, qx, fmaf(c.y, qy, fmaf(c.z, qz, c.w)));
        INS3(d, k, e0, e1, e2, i0, i1, i2);
    }
    #pragma unroll
    for (int o = 1; o < 64; o <<= 1) {
        float r0 = __shfl_xor(e0, o), r1 = __shfl_xor(e1, o), r2 = __shfl_xor(e2, o);
        int   s0 = __shfl_xor(i0, o), s1 = __shfl_xor(i1, o), s2 = __shfl_xor(i2, o);
        INS3(r0, s0, e0, e1, e2, i0, i1, i2);
        INS3(r1, s1, e0, e1, e2, i0, i1, i2);
        INS3(r2, s2, e0, e1, e2, i0, i1, i2);
    }
    if (ln == 0) {
        idw_write(qx, qy, qz, b * NPTS + i0, b * NPTS + i1, b * NPTS + i2,
                  ckey, cflow, out, b, origj);
    }
}

// ---------------------------------------------------------------------------
// Launcher. Workspace ~2.7 MB.
// ---------------------------------------------------------------------------
extern "C" void kernel_launch(void* const* d_in, const int* in_sizes, int n_in,
                              void* d_out, int out_size, void* d_ws, size_t ws_size,
                              hipStream_t stream)
{
    const float* xyz1  = (const float*)d_in[0];
    const float* xyz2  = (const float*)d_in[1];
    const float* flow1 = (const float*)d_in[2];
    float* out = (float*)d_out;

    char* p = (char*)d_ws;
    float4* ckey     = (float4*)p;  p += (size_t)BATCH * NPTS * 16;
    float4* cflow    = (float4*)p;  p += (size_t)BATCH * NPTS * 16;
    float4* qpos     = (float4*)p;  p += (size_t)BATCH * NPTS * 16;
    int*    counts_c = (int*)p;     p += (size_t)BATCH * NCP * 4;
    int*    counts_q = (int*)p;     p += (size_t)BATCH * QB * 4;
    int*    fbcnt    = (int*)p;     p += 16;
    int*    cstart   = (int*)p;     p += ((size_t)BATCH * NCP + 4) * 4;
    int*    ccur     = (int*)p;     p += (size_t)BATCH * NCP * 4;
    int*    qstart   = (int*)p;     p += ((size_t)BATCH * QB + 4) * 4;
    int*    qcur     = (int*)p;     p += (size_t)BATCH * QB * 4;
    int*    fblist   = (int*)p;

    // zero counts_c + counts_q + fbcnt in one shot (contiguous)
    hipMemsetAsync(counts_c, 0, (size_t)BATCH * (NCP + QB) * 4 + 16, stream);
    bin_both    <<<2 * BATCH * NPTS / 256, 256, 0, stream>>>(xyz1, xyz2, flow1, counts_c, counts_q);
    scan_chunks <<<8, 1024, 0, stream>>>(counts_c, cstart, ccur, counts_q, qstart, qcur);
    scatter_both<<<2 * BATCH * NPTS / 256, 256, 0, stream>>>(xyz1, xyz2, flow1, ccur, qcur, ckey, cflow, qpos);
    knn_tile    <<<BATCH * (NPTS / QPT), 256, 0, stream>>>(qpos, ckey, cflow, cstart, fbcnt, fblist, out);
    fb_wave     <<<BATCH * (NPTS / 4), 256, 0, stream>>>(qpos, ckey, cflow, fbcnt, fblist, out);
}

// Round 16
// 96.887 us; speedup vs baseline: 1.7498x; 1.3869x over previous
//
#include <hip/hip_runtime.h>
#include <math.h>

#define BATCH 4
#define NPTS 8192
#define GS 24                  // 24^3 cells of 0.5 over [-6,6]^3
#define NCP 16384              // padded cells per batch (24^3 = 13824)
#define GMIN (-6.0f)
#define CS 0.5f
#define INVCS 2.0f
#define FINF 3.4e38f
#define QPT 32                 // queries per tile
#define BUF 1536               // LDS staging slots (float4 + int idx)
#define NST 16                 // slot-streams (eval lanes per staged point)

__device__ __forceinline__ int cellc(float v) {
    int c = (int)((v - GMIN) * INVCS);
    return min(max(c, 0), GS - 1);
}

// branchless sorted top-3 update (R5-proven). Strict '<': incumbent wins ties.
#define INS3(d, idx, E0, E1, E2, I0, I1, I2) do {                     \
    bool c0 = (d) < E0, c1 = (d) < E1, c2 = (d) < E2;                 \
    float n1_ = __builtin_amdgcn_fmed3f(E0, E1, (d));                 \
    float n2_ = __builtin_amdgcn_fmed3f(E1, E2, (d));                 \
    I2 = c1 ? I1 : (c2 ? (idx) : I2);                                 \
    I1 = c0 ? I0 : (c1 ? (idx) : I1);                                 \
    I0 = c0 ? (idx) : I0;                                             \
    E0 = fminf(E0, (d)); E1 = n1_; E2 = n2_;                          \
} while (0)

// shared IDW epilogue: id* are global sorted candidate indices
__device__ __forceinline__ void idw_write(
    float qx, float qy, float qz, int n0, int n1, int n2,
    const float4* __restrict__ ckey, const float4* __restrict__ cflow,
    float* __restrict__ out, int b, int origj)
{
    float wsum = 0.f, f2x = 0.f, f2y = 0.f, f2z = 0.f;
    int idxs[3] = { n0, n1, n2 };
    #pragma unroll
    for (int k = 0; k < 3; ++k) {
        int id = idxs[k];
        float4 c = ckey[id];
        float cx = -0.5f * c.x, cy = -0.5f * c.y, cz = -0.5f * c.z;  // exact
        float dx = cx - qx, dy = cy - qy, dz = cz - qz;
        float dist = sqrtf(fmaf(dx, dx, fmaf(dy, dy, dz * dz)));
        dist = fmaxf(dist, 1e-10f);
        float w = 1.0f / dist;
        wsum += w;
        float4 fl = cflow[id];
        f2x = fmaf(w, fl.x, f2x);
        f2y = fmaf(w, fl.y, f2y);
        f2z = fmaf(w, fl.z, f2z);
    }
    float r = 1.0f / wsum;
    float* ob = out + b * 3 * NPTS;
    ob[origj]            = qx - f2x * r;
    ob[NPTS + origj]     = qy - f2y * r;
    ob[2 * NPTS + origj] = qz - f2z * r;
}

// ---------------------------------------------------------------------------
// K1: histogram candidates AND queries on the same padded linear grid.
// ---------------------------------------------------------------------------
__global__ __launch_bounds__(256) void bin_both(
    const float* __restrict__ xyz1, const float* __restrict__ xyz2,
    const float* __restrict__ flow1, int* __restrict__ counts_c,
    int* __restrict__ counts_q)
{
    int t = blockIdx.x * 256 + threadIdx.x;       // 2*BATCH*NPTS threads
    if (t < BATCH * NPTS) {
        int b = t >> 13, n = t & (NPTS - 1);
        const float* x = xyz1 + b * 3 * NPTS + n;
        const float* f = flow1 + b * 3 * NPTS + n;
        float wx = x[0] + f[0], wy = x[NPTS] + f[NPTS], wz = x[2*NPTS] + f[2*NPTS];
        int loc = (cellc(wz) * GS + cellc(wy)) * GS + cellc(wx);
        atomicAdd(&counts_c[b * NCP + loc], 1);
    } else {
        int tq = t - BATCH * NPTS;
        int b = tq >> 13, n = tq & (NPTS - 1);
        const float* q = xyz2 + b * 3 * NPTS + n;
        int loc = (cellc(q[2*NPTS]) * GS + cellc(q[NPTS])) * GS + cellc(q[0]);
        atomicAdd(&counts_q[b * NCP + loc], 1);
    }
}

// ---------------------------------------------------------------------------
// K2: exclusive prefix scan via shfl. 8 blocks: 0-3 candidate cells,
// 4-7 query cells; 4 chunks of 4096 each (int4/thread).
// ---------------------------------------------------------------------------
__global__ __launch_bounds__(1024) void scan_chunks(
    const int* __restrict__ cc, int* __restrict__ cs, int* __restrict__ ccur,
    const int* __restrict__ qc, int* __restrict__ qs, int* __restrict__ qcur)
{
    __shared__ int wsum[16];
    __shared__ int wpre[16];
    __shared__ int ctot;
    int blk = blockIdx.x, t = (int)threadIdx.x;
    int lane = t & 63, wid = t >> 6;
    const int* cnts; int* oS; int* oC; int batch;
    if (blk < 4) { batch = blk;     cnts = cc; oS = cs; oC = ccur; }
    else         { batch = blk - 4; cnts = qc; oS = qs; oC = qcur; }
    int base = batch * NCP;
    int carry = batch * NPTS;
    for (int ch = 0; ch < NCP; ch += 4096) {
        int4 v = *(const int4*)&cnts[base + ch + t * 4];
        int tsum = v.x + v.y + v.z + v.w;
        int incl = tsum;
        #pragma unroll
        for (int o = 1; o < 64; o <<= 1) {
            int n = __shfl_up(incl, o);
            if (lane >= o) incl += n;
        }
        if (lane == 63) wsum[wid] = incl;
        __syncthreads();
        if (t < 16) {
            int wv = wsum[t];
            int wincl = wv;
            #pragma unroll
            for (int o = 1; o < 16; o <<= 1) {
                int n = __shfl_up(wincl, o);
                if (t >= o) wincl += n;
            }
            wpre[t] = wincl - wv;
            if (t == 15) ctot = wincl;
        }
        __syncthreads();
        int excl = carry + wpre[wid] + (incl - tsum);
        int4 o4; o4.x = excl; o4.y = excl + v.x; o4.z = o4.y + v.y; o4.w = o4.z + v.z;
        *(int4*)&oS[base + ch + t * 4] = o4;
        *(int4*)&oC[base + ch + t * 4] = o4;
        carry += ctot;
        __syncthreads();
    }
    if (t == 0) oS[base + NCP] = carry;   // sentinel
}

// ---------------------------------------------------------------------------
// K3: scatter candidates (key+flow) AND queries (coords+orig idx) into
// cell-sorted order. One kernel, two halves of the grid.
// ---------------------------------------------------------------------------
__global__ __launch_bounds__(256) void scatter_both(
    const float* __restrict__ xyz1, const float* __restrict__ xyz2,
    const float* __restrict__ flow1, int* __restrict__ ccur,
    int* __restrict__ qcur, float4* __restrict__ ckey,
    float4* __restrict__ cflow, float4* __restrict__ qpos)
{
    int t = blockIdx.x * 256 + threadIdx.x;       // 2*BATCH*NPTS threads
    if (t < BATCH * NPTS) {
        int b = t >> 13, n = t & (NPTS - 1);
        const float* x = xyz1 + b * 3 * NPTS + n;
        const float* f = flow1 + b * 3 * NPTS + n;
        float fx = f[0], fy = f[NPTS], fz = f[2*NPTS];
        float wx = x[0] + fx, wy = x[NPTS] + fy, wz = x[2*NPTS] + fz;
        float nrm = fmaf(wx, wx, fmaf(wy, wy, wz * wz));
        int loc = (cellc(wz) * GS + cellc(wy)) * GS + cellc(wx);
        int pos = atomicAdd(&ccur[b * NCP + loc], 1);
        ckey[pos]  = make_float4(-2.0f*wx, -2.0f*wy, -2.0f*wz, nrm);
        cflow[pos] = make_float4(fx, fy, fz, 0.0f);
    } else {
        int tq = t - BATCH * NPTS;
        int b = tq >> 13, n = tq & (NPTS - 1);
        const float* q = xyz2 + b * 3 * NPTS + n;
        float qx = q[0], qy = q[NPTS], qz = q[2*NPTS];
        int loc = (cellc(qz) * GS + cellc(qy)) * GS + cellc(qx);
        int pos = atomicAdd(&qcur[b * NCP + loc], 1);
        qpos[pos] = make_float4(qx, qy, qz, __int_as_float(n));
    }
}

// ---------------------------------------------------------------------------
// K4: main pass — R12's accumulate-then-stream, widened to 8 waves.
// Block = 512 thr = 32 sorted queries (l = t&31) x 16 slot-streams (so =
// t>>5). Per z-slab: active queries (|hz-z|<=1) define a tight y/x window;
// per-row offsets via 64-lane shfl scan (identical in every wave); rows
// copied cooperatively (wave w takes rows w, w+8, ...) into a 1536-slot LDS
// buffer accumulating ACROSS slabs; streamed in long broadcast passes when
// full (each lane evaluates BUF/16 points - half of R12's per-lane eval).
// Resolve via per-query +-1-cell-box margin (grid-edge faces skipped) ->
// exact. Unresolved -> compacted per-batch fallback list.
// ---------------------------------------------------------------------------
#define STREAM(lim) do {                                              \
    for (int i_ = so; i_ < (lim); i_ += NST) {                        \
        float4 c_ = sc[i_];                                           \
        int kk_ = sidx[i_];                                           \
        float d_ = fmaf(c_.x, qx, fmaf(c_.y, qy, fmaf(c_.z, qz, c_.w))); \
        INS3(d_, kk_, e0, e1, e2, i0, i1, i2);                        \
    }                                                                 \
} while (0)

__global__ __launch_bounds__(512) void knn_tile(
    const float4* __restrict__ qpos, const float4* __restrict__ ckey,
    const float4* __restrict__ cflow, const int* __restrict__ cstart,
    int* __restrict__ fbcnt, int* __restrict__ fblist, float* __restrict__ out)
{
    __shared__ float4 sc[BUF];
    __shared__ int    sidx[BUF];
    float* md = (float*)&sc[0];                       // [16][32][3], aliases sc
    int*   mi = (int*)((char*)&sc[0] + 6144);         // next 6144 B of sc

    int tile = blockIdx.x;               // BATCH*256
    int b = tile >> 8, ti = tile & 255;
    int t = (int)threadIdx.x;
    int lane = t & 63, so = t >> 5, l = t & 31, w = t >> 6;
    int qbase = b * NPTS + ti * QPT;

    float4 qp = qpos[qbase + l];
    float qx = qp.x, qy = qp.y, qz = qp.z;
    int origj = __float_as_int(qp.w);
    float qn = fmaf(qx, qx, fmaf(qy, qy, qz * qz));
    int hx = cellc(qx), hy = cellc(qy), hz = cellc(qz);

    int zmn = hz, zmx = hz;
    #pragma unroll
    for (int o = 32; o >= 1; o >>= 1) {
        zmn = min(zmn, __shfl_xor(zmn, o));
        zmx = max(zmx, __shfl_xor(zmx, o));
    }
    int loz = max(zmn - 1, 0), hiz = min(zmx + 1, GS - 1);

    float e0 = FINF, e1 = FINF, e2 = FINF;
    int   i0 = 0, i1 = 0, i2 = 0;
    int bufofs = 0;
    int bN = b * NCP;

    for (int z = loz; z <= hiz; ++z) {
        bool act = (hz - z <= 1) && (z - hz <= 1);
        int ymn = act ? hy : 1000, ymx = act ? hy : -1000;
        int xmn = act ? hx : 1000, xmx = act ? hx : -1000;
        #pragma unroll
        for (int o = 32; o >= 1; o >>= 1) {
            ymn = min(ymn, __shfl_xor(ymn, o));
            ymx = max(ymx, __shfl_xor(ymx, o));
            xmn = min(xmn, __shfl_xor(xmn, o));
            xmx = max(xmx, __shfl_xor(xmx, o));
        }
        if (ymn == 1000) continue;                 // no query needs this slab
        int ylo = max(ymn - 1, 0), yhi = min(ymx + 1, GS - 1);
        int xlo = max(xmn - 1, 0), xhi = min(xmx + 1, GS - 1);
        int nrows = yhi - ylo + 1;                 // <= 24 < 64

        int strt = 0, rlen = 0;
        if (lane < nrows) {
            int rb = bN + (z * GS + (ylo + lane)) * GS;
            strt = cstart[rb + xlo];
            rlen = cstart[rb + xhi + 1] - strt;
        }
        int incl = rlen;
        #pragma unroll
        for (int o = 1; o < 64; o <<= 1) {
            int n = __shfl_up(incl, o);
            if (lane >= o) incl += n;
        }
        int excl = incl - rlen;
        int T = __shfl(incl, 63);

        int copied = 0;
        while (copied < T) {                       // uniform loop
            int cnt = min(T - copied, BUF - bufofs);
            for (int r = w; r < nrows; r += 8) {   // wave w copies rows w,w+8,..
                int rofs = __shfl(excl, r);
                int rst  = __shfl(strt, r);
                int rln  = __shfl(rlen, r);
                int lo = max(rofs, copied), hi = min(rofs + rln, copied + cnt);
                for (int i = lo + lane; i < hi; i += 64) {
                    int dst = bufofs + (i - copied);
                    int src = rst + (i - rofs);
                    sc[dst] = ckey[src];
                    sidx[dst] = src;
                }
            }
            bufofs += cnt; copied += cnt;
            if (bufofs == BUF) {                   // uniform
                __syncthreads();
                STREAM(BUF);
                __syncthreads();
                bufofs = 0;
            }
        }
    }
    __syncthreads();
    if (bufofs > 0) STREAM(bufofs);                // uniform
    __syncthreads();                               // sc reused as md/mi below

    md[(so * 32 + l) * 3 + 0] = e0;  mi[(so * 32 + l) * 3 + 0] = i0;
    md[(so * 32 + l) * 3 + 1] = e1;  mi[(so * 32 + l) * 3 + 1] = i1;
    md[(so * 32 + l) * 3 + 2] = e2;  mi[(so * 32 + l) * 3 + 2] = i2;
    __syncthreads();

    if (t < QPT) {
        float m0 = FINF, m1 = FINF, m2 = FINF;
        int   n0 = 0, n1 = 0, n2 = 0;
        #pragma unroll
        for (int ss = 0; ss < NST; ++ss) {
            int bx = (ss * 32 + t) * 3;
            INS3(md[bx],     mi[bx],     m0, m1, m2, n0, n1, n2);
            INS3(md[bx + 1], mi[bx + 1], m0, m1, m2, n0, n1, n2);
            INS3(md[bx + 2], mi[bx + 2], m0, m1, m2, n0, n1, n2);
        }
        // per-query margin: distance to own +-1-cell-box faces (grid-edge skipped)
        float mg = FINF;
        if (hx > 1)      mg = fminf(mg, qx - (GMIN + (hx - 1) * CS));
        if (hx < GS - 2) mg = fminf(mg, (GMIN + (hx + 2) * CS) - qx);
        if (hy > 1)      mg = fminf(mg, qy - (GMIN + (hy - 1) * CS));
        if (hy < GS - 2) mg = fminf(mg, (GMIN + (hy + 2) * CS) - qy);
        if (hz > 1)      mg = fminf(mg, qz - (GMIN + (hz - 1) * CS));
        if (hz < GS - 2) mg = fminf(mg, (GMIN + (hz + 2) * CS) - qz);
        if (m2 + qn <= mg * mg) {
            idw_write(qx, qy, qz, n0, n1, n2, ckey, cflow, out, b, origj);
        } else {
            int p = atomicAdd(&fbcnt[b], 1);
            fblist[b * NPTS + p] = ti * QPT + t;   // batch-local sorted position
        }
    }
}

// ---------------------------------------------------------------------------
// K5: wave-per-query fallback (R12-proven). Lane ln scans candidates
// ln, ln+64, ... (coalesced vector loads), butterfly shfl merge, lane 0
// writes. Worst-case grid, wave-uniform early exit.
// ---------------------------------------------------------------------------
__global__ __launch_bounds__(256) void fb_wave(
    const float4* __restrict__ qpos, const float4* __restrict__ ckey,
    const float4* __restrict__ cflow, const int* __restrict__ fbcnt,
    const int* __restrict__ fblist, float* __restrict__ out)
{
    int blk = blockIdx.x;                 // BATCH * NPTS/4 = 8192
    int b = blk >> 11, grp = blk & 2047;
    int t = (int)threadIdx.x;
    int w = t >> 6, ln = t & 63;
    int cnt = fbcnt[b];
    int idx = grp * 4 + w;
    if (idx >= cnt) return;               // wave-uniform exit

    int js = fblist[b * NPTS + idx];
    float4 qp = qpos[b * NPTS + js];
    float qx = qp.x, qy = qp.y, qz = qp.z;
    int origj = __float_as_int(qp.w);

    const float4* src = ckey + b * NPTS;

    float e0 = FINF, e1 = FINF, e2 = FINF;
    int   i0 = 0, i1 = 0, i2 = 0;
    #pragma unroll 4
    for (int k = ln; k < NPTS; k += 64) {
        float4 c = src[k];
        float d = fmaf(c.x, qx, fmaf(c.y, qy, fmaf(c.z, qz, c.w)));
        INS3(d, k, e0, e1, e2, i0, i1, i2);
    }
    #pragma unroll
    for (int o = 1; o < 64; o <<= 1) {
        float r0 = __shfl_xor(e0, o), r1 = __shfl_xor(e1, o), r2 = __shfl_xor(e2, o);
        int   s0 = __shfl_xor(i0, o), s1 = __shfl_xor(i1, o), s2 = __shfl_xor(i2, o);
        INS3(r0, s0, e0, e1, e2, i0, i1, i2);
        INS3(r1, s1, e0, e1, e2, i0, i1, i2);
        INS3(r2, s2, e0, e1, e2, i0, i1, i2);
    }
    if (ln == 0) {
        idw_write(qx, qy, qz, b * NPTS + i0, b * NPTS + i1, b * NPTS + i2,
                  ckey, cflow, out, b, origj);
    }
}

// ---------------------------------------------------------------------------
// Launcher. Workspace ~3.1 MB.
// ---------------------------------------------------------------------------
extern "C" void kernel_launch(void* const* d_in, const int* in_sizes, int n_in,
                              void* d_out, int out_size, void* d_ws, size_t ws_size,
                              hipStream_t stream)
{
    const float* xyz1  = (const float*)d_in[0];
    const float* xyz2  = (const float*)d_in[1];
    const float* flow1 = (const float*)d_in[2];
    float* out = (float*)d_out;

    char* p = (char*)d_ws;
    float4* ckey     = (float4*)p;  p += (size_t)BATCH * NPTS * 16;
    float4* cflow    = (float4*)p;  p += (size_t)BATCH * NPTS * 16;
    float4* qpos     = (float4*)p;  p += (size_t)BATCH * NPTS * 16;
    int*    counts_c = (int*)p;     p += (size_t)BATCH * NCP * 4;
    int*    counts_q = (int*)p;     p += (size_t)BATCH * NCP * 4;
    int*    fbcnt    = (int*)p;     p += 16;
    int*    cstart   = (int*)p;     p += ((size_t)BATCH * NCP + 4) * 4;
    int*    ccur     = (int*)p;     p += (size_t)BATCH * NCP * 4;
    int*    qstart   = (int*)p;     p += ((size_t)BATCH * NCP + 4) * 4;
    int*    qcur     = (int*)p;     p += (size_t)BATCH * NCP * 4;
    int*    fblist   = (int*)p;

    // zero counts_c + counts_q + fbcnt in one shot (contiguous)
    hipMemsetAsync(counts_c, 0, (size_t)BATCH * NCP * 4 * 2 + 16, stream);
    bin_both    <<<2 * BATCH * NPTS / 256, 256, 0, stream>>>(xyz1, xyz2, flow1, counts_c, counts_q);
    scan_chunks <<<8, 1024, 0, stream>>>(counts_c, cstart, ccur, counts_q, qstart, qcur);
    scatter_both<<<2 * BATCH * NPTS / 256, 256, 0, stream>>>(xyz1, xyz2, flow1, ccur, qcur, ckey, cflow, qpos);
    knn_tile    <<<BATCH * (NPTS / QPT), 512, 0, stream>>>(qpos, ckey, cflow, cstart, fbcnt, fblist, out);
    fb_wave     <<<BATCH * (NPTS / 4), 256, 0, stream>>>(qpos, ckey, cflow, fbcnt, fblist, out);
}